// Round 18
// baseline (615.839 us; speedup 1.0000x reference)
//
#include <hip/hip_runtime.h>
#include <math.h>

#define TS 10
#define TD 128
#define TE 64
#define BT 8
#define NTHR 256
#define HSTR 132          // floats per Hs row: 128+4 pad (t1 lives in cols 0..63)
#define QSTR 68           // floats per Q/K/Vd/G row: 64+4 pad
#define NHROWS (TS*BT)    // 80

#define HS_FLOATS (NHROWS*HSTR)    // 10560
#define BUF_FLOATS (40*QSTR)       // 2720 (half-batch 40-row buffer)
#define P_FLOATS (BT*TS*12)        // 960
#define LDS_FLOATS (HS_FLOATS + 3*BUF_FLOATS + P_FLOATS)   // 19680 -> 78720 B (2 WG/CU)

#define INVSQRT10 0.31622776601683794f

// workspace float offsets (layout unchanged from R17)
#define WS_POS   0        // POS[10][128]             (1280)  [unused by trans now]
#define WS_LW    1280     // LW[p][c][e] 3x4x64       (768)
#define WS_PW    2048     // PW[p][n][e] 3x10x64      (1920)
#define WS_ZW    3968     // ZW[n][c][e] 10x4x64      (2560)
#define WS_LQ    6528     // LQ[n][c][k] 10x4x64      (2560)
#define WS_PQ    9088     // PQ[n][k]    10x64        (640)
#define WS_ZQ    9728     // ZQ[n][c][k] 10x4x64      (2560)
#define WS_WVUQ  12288    // WVuQ[n][e][k] 10x64x64   (40960)
#define WS_W2N   53248    // W2N[p][n][k][e] 3x10x64x64 (122880) -> end 176128 (705 KB)

typedef float v2f __attribute__((ext_vector_type(2)));

// Broadcast-free packed FMA via VOP3P op_sel (bit-identical IEEE fp32 fma),
// R7-proven; keeps the deep-prefetch gemm spill-free at the 128-VGPR cap.
#define PKFMA_LO(acc_, ap_, wp_) \
    asm("v_pk_fma_f32 %0, %1, %2, %0 op_sel:[0,0,0] op_sel_hi:[0,1,1]" \
        : "+v"(acc_) : "v"(ap_), "v"(wp_))
#define PKFMA_HI(acc_, ap_, wp_) \
    asm("v_pk_fma_f32 %0, %1, %2, %0 op_sel:[1,0,0] op_sel_hi:[1,1,1]" \
        : "+v"(acc_) : "v"(ap_), "v"(wp_))

// Wave-synchronous LDS fence (R8/R13-validated): sufficient for same-wave
// LDS RAW deps; replaces __syncthreads inside the wave-local attention chain.
#define WSYNC() do { __builtin_amdgcn_wave_barrier(); \
    asm volatile("s_waitcnt lgkmcnt(0)" ::: "memory"); \
    __builtin_amdgcn_wave_barrier(); } while (0)

__device__ __forceinline__ float pos_val(int n, int d) {
    int j = d >> 1;
    double ang = (double)n / pow(1000.0, 2.0 * (double)j / (double)TD);
    return (float)((d & 1) ? cos(ang) : sin(ang));
}

// ---------------- pre-kernel (once per launch, into d_ws) -------------------
// R18: prelude v3 — 111 dependency-free blocks; qin1 column reads staged
// through LDS (32KB coalesced copy, conflict-free column access); W2N split
// 2-way over k; PQ's POS row recomputed locally (no cross-block dep).
//   bid 0       : POS table + LW + PW
//   bid 1..10   : per-n {stage qin1[n] -> LDS} then LQ[n], PQ[n], WVuQ[n]
//   bid 11..70  : W2N[p][n] half-k (60 blocks)
//   bid 71..110 : per-(n,c) chain P2row -> Zrow -> {ZW,ZQ} (40 blocks)
// All table formulas identical to R16/R17 (numerically validated).
__global__ void pre_kernel(float* __restrict__ ws,
                           const float* __restrict__ L_w,
                           const float* __restrict__ WQ,
                           const float* __restrict__ WK,
                           const float* __restrict__ WVd,
                           const float* __restrict__ qin2,
                           const float* __restrict__ qout2,
                           const float* __restrict__ UL_w,
                           const float* __restrict__ WVu2,
                           const float* __restrict__ qin1,
                           const float* __restrict__ WVu,
                           const float* __restrict__ qout1,
                           const float* __restrict__ WQ2,
                           const float* __restrict__ WK2,
                           const float* __restrict__ WVd2) {
    const int tid = threadIdx.x;
    const int bid = blockIdx.x;

    if (bid == 0) {
        __shared__ float sPOS[TS * TD];
        for (int idx = tid; idx < TS * TD; idx += 256) {
            float v = pos_val(idx / TD, idx % TD);
            sPOS[idx] = v;
            ws[WS_POS + idx] = v;
        }
        __syncthreads();
        // LW[p][c][e]
        for (int idx = tid; idx < 3 * 4 * TE; idx += 256) {
            int p = idx >> 8, r = idx & 255, c = r >> 6, e = r & 63;
            const float* Wp = (p == 0 ? WQ : (p == 1 ? WK : WVd));
            const float* lr = L_w + c * TD;
            float acc = 0.f;
            for (int d = 0; d < TD; d++) acc = fmaf(lr[d], Wp[d * TE + e], acc);
            ws[WS_LW + idx] = acc;
        }
        // PW[p][n][e]
        for (int idx = tid; idx < 3 * TS * TE; idx += 256) {
            int p = idx / 640, r = idx % 640, n = r >> 6, e = r & 63;
            const float* Wp = (p == 0 ? WQ : (p == 1 ? WK : WVd));
            const float* pr = sPOS + n * TD;
            float acc = 0.f;
            for (int d = 0; d < TD; d++) acc = fmaf(pr[d], Wp[d * TE + e], acc);
            ws[WS_PW + idx] = acc;
        }
        return;
    }
    if (bid <= 10) {   // per-n: LQ + PQ + WVuQ from LDS-staged qin1[n]
        int n = bid - 1;
        __shared__ float sQ[TD * TE];     // qin1[n], [d][k] row-major (32 KB)
        __shared__ float sPOSn[TD];
        for (int idx = tid; idx < TD * TE / 4; idx += 256)
            *(float4*)(sQ + idx * 4) =
                *(const float4*)(qin1 + (size_t)n * TD * TE + idx * 4);
        if (tid < TD) sPOSn[tid] = pos_val(n, tid);
        __syncthreads();
        // LQ[n][c][k] (256) + PQ[n][k] (64): 320 tasks
        for (int t = tid; t < 320; t += 256) {
            if (t < 256) {
                int c = t >> 6, k = t & 63;
                const float* lr = L_w + c * TD;
                float acc = 0.f;
                for (int d = 0; d < TD; d++) acc = fmaf(lr[d], sQ[d * TE + k], acc);
                ws[WS_LQ + n * 256 + t] = acc;
            } else {
                int k = t - 256;
                float acc = 0.f;
                for (int d = 0; d < TD; d++) acc = fmaf(sPOSn[d], sQ[d * TE + k], acc);
                ws[WS_PQ + n * TE + k] = acc;
            }
        }
        // WVuQ[n][e][k] = sum_d WVu[e][d]*qin1[n][d][k]
        float* dst = ws + WS_WVUQ + n * 4096;
        for (int idx = tid; idx < TE * TE; idx += 256) {
            int e = idx >> 6, k = idx & 63;
            const float* wv = WVu + (size_t)e * TD;
            float acc = 0.f;
            for (int d = 0; d < TD; d += 4) {
                float4 w4 = *(const float4*)(wv + d);
                acc = fmaf(w4.x, sQ[(d + 0) * TE + k], acc);
                acc = fmaf(w4.y, sQ[(d + 1) * TE + k], acc);
                acc = fmaf(w4.z, sQ[(d + 2) * TE + k], acc);
                acc = fmaf(w4.w, sQ[(d + 3) * TE + k], acc);
            }
            dst[idx] = acc;
        }
        return;
    }
    if (bid <= 70) {   // W2N[p][n], half-k per block (60 blocks)
        int t = bid - 11;
        int half = t & 1, pn = t >> 1;
        int p = pn / 10, n = pn % 10;
        const float* Wp = (p == 0 ? WQ2 : (p == 1 ? WK2 : WVd2));
        float* dst = ws + WS_W2N + (pn << 12);
        for (int idx = tid; idx < 2048; idx += 256) {
            int k = half * 32 + (idx >> 6), e = idx & 63;
            const float* qp = qout1 + ((size_t)n * TE + k) * TD;
            float acc = 0.f;
            for (int j = 0; j < TD; j += 4) {
                float4 q4 = *(const float4*)(qp + j);
                acc = fmaf(q4.x, Wp[(j + 0) * TE + e], acc);
                acc = fmaf(q4.y, Wp[(j + 1) * TE + e], acc);
                acc = fmaf(q4.z, Wp[(j + 2) * TE + e], acc);
                acc = fmaf(q4.w, Wp[(j + 3) * TE + e], acc);
            }
            dst[k * TE + e] = acc;
        }
        return;
    }
    // bid 71..110: (n,c) chain: P2 row -> Z row -> ZW + ZQ rows
    {
        int t = bid - 71, n = t >> 2, c = t & 3;
        __shared__ float sP2r[TE];    // P2[n][c][:]
        __shared__ float sZr[TD];     // Z[n][c][:]
        if (tid < TE) {   // P2[n][c][i] = sum_d qout2[n][i][d]*UL_w[d][c]
            int i = tid;
            const float* qp = qout2 + ((size_t)n * TE + i) * TD;
            float acc = 0.f;
            for (int d = 0; d < TD; d += 4) {
                float4 q4 = *(const float4*)(qp + d);
                acc = fmaf(q4.x, UL_w[(d + 0) * 4 + c], acc);
                acc = fmaf(q4.y, UL_w[(d + 1) * 4 + c], acc);
                acc = fmaf(q4.z, UL_w[(d + 2) * 4 + c], acc);
                acc = fmaf(q4.w, UL_w[(d + 3) * 4 + c], acc);
            }
            sP2r[i] = acc;
        }
        __syncthreads();
        if (tid < TD) {   // Z[n][c][j] = sum_i qin2[n][j][i]*P2[n][c][i]
            int j = tid;
            const float* ip = qin2 + ((size_t)n * TD + j) * TE;
            float acc = 0.f;
            for (int i = 0; i < TE; i += 4) {
                float4 q4 = *(const float4*)(ip + i);
                acc = fmaf(q4.x, sP2r[i + 0], acc);
                acc = fmaf(q4.y, sP2r[i + 1], acc);
                acc = fmaf(q4.z, sP2r[i + 2], acc);
                acc = fmaf(q4.w, sP2r[i + 3], acc);
            }
            sZr[j] = acc;
        }
        __syncthreads();
        if (tid < TE) {   // ZW[n][c][e] = sum_j WVu2[e][j]*Z[n][c][j]
            int e = tid;
            const float* wp = WVu2 + (size_t)e * TD;
            float acc = 0.f;
            for (int j = 0; j < TD; j += 4) {
                float4 w4 = *(const float4*)(wp + j);
                acc = fmaf(w4.x, sZr[j + 0], acc);
                acc = fmaf(w4.y, sZr[j + 1], acc);
                acc = fmaf(w4.z, sZr[j + 2], acc);
                acc = fmaf(w4.w, sZr[j + 3], acc);
            }
            ws[WS_ZW + (n * 4 + c) * TE + e] = acc;
        } else if (tid < 2 * TE) {   // ZQ[n][c][k] = sum_j qout1[n][k][j]*Z[n][c][j]
            int k = tid - TE;
            const float* qp = qout1 + ((size_t)n * TE + k) * TD;
            float acc = 0.f;
            for (int j = 0; j < TD; j += 4) {
                float4 q4 = *(const float4*)(qp + j);
                acc = fmaf(q4.x, sZr[j + 0], acc);
                acc = fmaf(q4.y, sZr[j + 1], acc);
                acc = fmaf(q4.z, sZr[j + 2], acc);
                acc = fmaf(q4.w, sZr[j + 3], acc);
            }
            ws[WS_ZQ + (n * 4 + c) * TE + k] = acc;
        }
    }
}

// ---------------- M-row x C-col fp32 GEMM tile, packed-pair FMAs ------------
// Deep W-prefetch (R5/R6) + op_sel pk-fma (R7): spill-free at cap 128.
template <int M, int SPLIT, int C, int K, bool ADD>
__device__ __forceinline__ void gemm_f32(
    const float* __restrict__ Ap, int a0, int aHi, int aLo,
    const float* __restrict__ W, int ws,
    float* __restrict__ Op, int o0, int oHi, int oLo,
    float scale)
{
    static_assert(C % 4 == 0, "C must be a multiple of 4");
    static_assert(K % 16 == 0 && K >= 32, "K must be a multiple of 16, >=32");
    constexpr int CG = C / 4;   // float4 groups
    constexpr int CP = C / 2;   // float2 pairs
    v2f acc[M][CP];
#pragma unroll
    for (int m = 0; m < M; m++)
#pragma unroll
        for (int p = 0; p < CP; p++) acc[m][p] = (v2f)(0.f);

    float4 aR0[M], aR1[M];
    float4 wA[8 * CG], wB[8 * CG];      // ping-pong 8-k W buffers
    const float* ap = Ap + a0;
    const float* wp = W;

    auto loadW8 = [&](float4* wR, const float* w) {
#pragma unroll
        for (int kk = 0; kk < 8; kk++)
#pragma unroll
            for (int cg = 0; cg < CG; cg++)
                wR[kk * CG + cg] = *(const float4*)(w + kk * ws + cg * 4);
    };
    auto loadA = [&](float4* aR, const float* a) {
#pragma unroll
        for (int m = 0; m < M; m++)
            aR[m] = *(const float4*)(a + (m / SPLIT) * aHi + (m % SPLIT) * aLo);
    };
    auto computeH = [&](const float4* aR, const float4* wR) {
#pragma unroll
        for (int m = 0; m < M; m++) {
            const v2f* ap2 = (const v2f*)&aR[m];    // (a0,a1),(a2,a3)
#pragma unroll
            for (int kp = 0; kp < 2; kp++) {
                const v2f* wf0 = (const v2f*)&wR[(2 * kp + 0) * CG];
                const v2f* wf1 = (const v2f*)&wR[(2 * kp + 1) * CG];
#pragma unroll
                for (int p = 0; p < CP; p++) {
                    PKFMA_LO(acc[m][p], ap2[kp], wf0[p]);   // k = 2kp
                    PKFMA_HI(acc[m][p], ap2[kp], wf1[p]);   // k = 2kp+1
                }
            }
        }
    };

    loadW8(wA, wp);
    loadA(aR0, ap);
#pragma unroll 1
    for (int k = 0; k + 16 < K; k += 16) {
        loadW8(wB, wp + 8 * ws);
        loadA(aR1, ap + 4);
        computeH(aR0, wA);
        loadA(aR0, ap + 8);
        computeH(aR1, wA + 4 * CG);
        loadW8(wA, wp + 16 * ws);
        loadA(aR1, ap + 12);
        computeH(aR0, wB);
        loadA(aR0, ap + 16);
        computeH(aR1, wB + 4 * CG);
        wp += 16 * ws; ap += 16;
    }
    loadW8(wB, wp + 8 * ws);
    loadA(aR1, ap + 4);
    computeH(aR0, wA);
    loadA(aR0, ap + 8);
    computeH(aR1, wA + 4 * CG);
    loadA(aR1, ap + 12);
    computeH(aR0, wB);
    computeH(aR1, wB + 4 * CG);

    v2f s2; s2.x = scale; s2.y = scale;
#pragma unroll
    for (int m = 0; m < M; m++) {
        float* op = Op + o0 + (m / SPLIT) * oHi + (m % SPLIT) * oLo;
#pragma unroll
        for (int cg = 0; cg < CG; cg++) {
            float4 r;
            v2f* rp = (v2f*)&r;
            if constexpr (ADD) {
                float4 v = *(float4*)(op + cg * 4);
                const v2f* vp = (const v2f*)&v;
                rp[0] = s2 * acc[m][cg * 2 + 0] + vp[0];
                rp[1] = s2 * acc[m][cg * 2 + 1] + vp[1];
            } else {
                rp[0] = s2 * acc[m][cg * 2 + 0];
                rp[1] = s2 * acc[m][cg * 2 + 1];
            }
            *(float4*)(op + cg * 4) = r;
        }
    }
}

// ---------------- fused kernel ----------------------------------------------
// Identical to R16/R17 (456-463us steady, proven): rank-64 layer-2 collapse
// (QKV-l2 = t1@W2N K=64; quesout1 deleted; out = t1.ZQ + s*G2.ZW),
// rank-4 layer-1 QKV, qin1 fold (t1 = x@LQ + PQ + s*G1@WVuQ),
// wave-local attention chains with WSYNC.
// BT=8, 78.72 KB LDS -> 2 WG/CU; VGPR<=128 (cliff at 128/129, R5);
// launch_bounds(256,2) pins the cap (R0/R6/R7/R10/R11-proven).
extern "C" __global__ __launch_bounds__(NTHR, 2)
void trans_fused(const float* __restrict__ x,
                 const float* __restrict__ L_w, const float* __restrict__ UL_w,
                 const float* __restrict__ WQ,  const float* __restrict__ WK,
                 const float* __restrict__ WVd, const float* __restrict__ WVu,
                 const float* __restrict__ WQ2, const float* __restrict__ WK2,
                 const float* __restrict__ WVd2,const float* __restrict__ WVu2,
                 const float* __restrict__ qin1,const float* __restrict__ qout1,
                 const float* __restrict__ qin2,const float* __restrict__ qout2,
                 const float* __restrict__ POSb, float* __restrict__ out)
{
    extern __shared__ float lds[];
    float* Hs = lds;                      // [80][HSTR]; t1 in cols 0..63 (persistent)
    float* Qb = lds + HS_FLOATS;          // [40][QSTR]; Q then G (per hb)
    float* Kb = Qb + BUF_FLOATS;          // [40][QSTR]
    float* Vb = Kb + BUF_FLOATS;          // [40][QSTR] Vd
    float* Pb = Vb + BUF_FLOATS;          // [8][10][12] logits -> softmax weights

    const int tid = threadIdx.x;
    const int vtid = (tid + ((blockIdx.x & 3) << 6)) & 255;  // rotate idle windows
    const int w = vtid >> 6;              // wave-local batch index b4 (wave-aligned)
    const int l = vtid & 63;
    const int gb0 = blockIdx.x * BT;
    const float* LWb   = POSb + WS_LW;
    const float* PWb   = POSb + WS_PW;
    const float* ZWb   = POSb + WS_ZW;
    const float* LQb   = POSb + WS_LQ;
    const float* PQb   = POSb + WS_PQ;
    const float* ZQb   = POSb + WS_ZQ;
    const float* WVuQb = POSb + WS_WVUQ;
    const float* W2Nb  = POSb + WS_W2N;

    // ================= LAYER 1 (h never materialized) =================
    for (int hb = 0; hb < 2; ++hb) {
        // ---- QKV-l1 rank-4 (1920 tasks) + t1base = x@LQ + PQ (640 tasks) ----
        for (int t = vtid; t < 2560; t += NTHR) {
            if (t < 1920) {
                int p = t / 640, r2 = t % 640, rr = r2 >> 4, e4 = r2 & 15;
                int b4 = rr / 10, n = rr - b4 * 10;
                const float* xp = x + ((size_t)(gb0 + hb * 4 + b4) * TS + n) * 4;
                float4 x4 = *(const float4*)xp;
                const float* xf = (const float*)&x4;
                const float* lw = LWb + p * 256 + e4 * 4;
                float4 pw = *(const float4*)(PWb + p * 640 + n * 64 + e4 * 4);
                v2f a0 = ((const v2f*)&pw)[0], a1 = ((const v2f*)&pw)[1];
#pragma unroll
                for (int c = 0; c < 4; c++) {
                    float4 l4 = *(const float4*)(lw + c * 64);
                    v2f xb; xb.x = xf[c]; xb.y = xf[c];
                    a0 = xb * ((const v2f*)&l4)[0] + a0;
                    a1 = xb * ((const v2f*)&l4)[1] + a1;
                }
                float* Ob = (p == 0 ? Qb : (p == 1 ? Kb : Vb));
                float4 r4;
                ((v2f*)&r4)[0] = a0; ((v2f*)&r4)[1] = a1;
                *(float4*)(Ob + rr * QSTR + e4 * 4) = r4;
            } else {
                int t2 = t - 1920;              // 0..639
                int rr = t2 >> 4, cg = t2 & 15;
                int b4 = rr / 10, n = rr - b4 * 10;
                const float* xp = x + ((size_t)(gb0 + hb * 4 + b4) * TS + n) * 4;
                float4 x4 = *(const float4*)xp;
                const float* xf = (const float*)&x4;
                const float* lq = LQb + n * 256 + cg * 4;
                float4 pq = *(const float4*)(PQb + n * 64 + cg * 4);
                v2f a0 = ((const v2f*)&pq)[0], a1 = ((const v2f*)&pq)[1];
#pragma unroll
                for (int c = 0; c < 4; c++) {
                    float4 l4 = *(const float4*)(lq + c * 64);
                    v2f xb; xb.x = xf[c]; xb.y = xf[c];
                    a0 = xb * ((const v2f*)&l4)[0] + a0;
                    a1 = xb * ((const v2f*)&l4)[1] + a1;
                }
                float4 r4;
                ((v2f*)&r4)[0] = a0; ((v2f*)&r4)[1] = a1;
                *(float4*)(Hs + (hb * 40 + rr) * HSTR + cg * 4) = r4;
            }
        }
        __syncthreads();

        // ---- logits: 55 (i,j<=i) pairs, one lane each; own batch ----
        if (l < 55) {
            int i = 0, base = 0, pr = l;
            while (pr >= base + i + 1) { base += i + 1; i++; }
            int j = pr - base;
            const float* qr = Qb + (w * 10 + i) * QSTR;
            const float* kr = Kb + (w * 10 + j) * QSTR;
            v2f s0 = (v2f)(0.f), s1 = (v2f)(0.f);
            for (int e = 0; e < TE; e += 8) {
                float4 qa = *(const float4*)(qr + e);
                float4 ka = *(const float4*)(kr + e);
                float4 qc = *(const float4*)(qr + e + 4);
                float4 kc = *(const float4*)(kr + e + 4);
                s0 = ((const v2f*)&qa)[0] * ((const v2f*)&ka)[0] + s0;
                s1 = ((const v2f*)&qa)[1] * ((const v2f*)&ka)[1] + s1;
                s0 = ((const v2f*)&qc)[0] * ((const v2f*)&kc)[0] + s0;
                s1 = ((const v2f*)&qc)[1] * ((const v2f*)&kc)[1] + s1;
            }
            Pb[(hb * 4 + w) * 120 + i * 12 + j] = (s0.x + s0.y) + (s1.x + s1.y);
        }
        WSYNC();

        // ---- softmax over keys j<=i (own batch) ----
        if (l < TS) {
            float* pr = Pb + (hb * 4 + w) * 120 + l * 12;
            float m = pr[0];
#pragma unroll
            for (int j = 1; j < TS; j++) if (j <= l) m = fmaxf(m, pr[j]);
            float sum = 0.f;
#pragma unroll
            for (int j = 0; j < TS; j++) if (j <= l) { float e = expf(pr[j] - m); pr[j] = e; sum += e; }
#pragma unroll
            for (int j = 0; j < TS; j++) pr[j] = (j <= l) ? pr[j] / sum : 0.f;
        }
        WSYNC();

        // ---- G[q][e] (own batch): 160 tasks per wave; into Qb (Q dead) ----
        for (int oi = l; oi < 160; oi += 64) {
            int q = oi >> 4, e4 = (oi & 15) * 4;
            const float* pp = Pb + (hb * 4 + w) * 120 + q * 12;
            v2f g0 = (v2f)(0.f), g1 = (v2f)(0.f);
#pragma unroll
            for (int k = 0; k < TS; k++) {
                float p = pp[k];
                v2f pv; pv.x = p; pv.y = p;
                float4 v = *(const float4*)(Vb + (w * 10 + k) * QSTR + e4);
                g0 = pv * ((const v2f*)&v)[0] + g0;
                g1 = pv * ((const v2f*)&v)[1] + g1;
            }
            float4 g;
            ((v2f*)&g)[0] = g0; ((v2f*)&g)[1] = g1;
            *(float4*)(Qb + (w * 10 + q) * QSTR + e4) = g;
        }
        __syncthreads();   // t1gemm groups rows across waves (M=4 over b4)

        // ---- t1 += s * G @ WVuQ[n]: 160 tasks = n(10) x cg(16), M=4, K=64 ----
        if (vtid < 160) {
            int n = vtid >> 4, cg = vtid & 15;
            gemm_f32<4, 1, 4, TE, true>(
                Qb, n * QSTR, 10 * QSTR, 0,
                WVuQb + n * 4096 + cg * 4, TE,
                Hs, (hb * 40 + n) * HSTR + cg * 4, 10 * HSTR, 0,
                INVSQRT10);
        }
        __syncthreads();
    } // hb layer 1

    // ================= LAYER 2 (rank-64 collapsed; t1 stays in Hs) ==========
    for (int hb = 0; hb < 2; ++hb) {
        // ---- QKV-l2: Q2/K2/V2 = t1 @ W2N[p][n]; 480 tasks, M=4, K=64 ----
        for (int t = vtid; t < 480; t += NTHR) {
            int p = t / 160, rem = t - p * 160, n = rem >> 4, cg = rem & 15;
            float* Ob = (p == 0 ? Qb : (p == 1 ? Kb : Vb));
            gemm_f32<4, 1, 4, TE, false>(
                Hs, (hb * 40 + n) * HSTR, 10 * HSTR, 0,
                W2Nb + ((p * 10 + n) << 12) + cg * 4, TE,
                Ob, n * QSTR + cg * 4, 10 * QSTR, 0, 1.f);
        }
        __syncthreads();

        // ---- logits2 (wave-local) ----
        if (l < 55) {
            int i = 0, base = 0, pr = l;
            while (pr >= base + i + 1) { base += i + 1; i++; }
            int j = pr - base;
            const float* qr = Qb + (w * 10 + i) * QSTR;
            const float* kr = Kb + (w * 10 + j) * QSTR;
            v2f s0 = (v2f)(0.f), s1 = (v2f)(0.f);
            for (int e = 0; e < TE; e += 8) {
                float4 qa = *(const float4*)(qr + e);
                float4 ka = *(const float4*)(kr + e);
                float4 qc = *(const float4*)(qr + e + 4);
                float4 kc = *(const float4*)(kr + e + 4);
                s0 = ((const v2f*)&qa)[0] * ((const v2f*)&ka)[0] + s0;
                s1 = ((const v2f*)&qa)[1] * ((const v2f*)&ka)[1] + s1;
                s0 = ((const v2f*)&qc)[0] * ((const v2f*)&kc)[0] + s0;
                s1 = ((const v2f*)&qc)[1] * ((const v2f*)&kc)[1] + s1;
            }
            Pb[(hb * 4 + w) * 120 + i * 12 + j] = (s0.x + s0.y) + (s1.x + s1.y);
        }
        WSYNC();

        // ---- softmax2 (own batch) ----
        if (l < TS) {
            float* pr = Pb + (hb * 4 + w) * 120 + l * 12;
            float m = pr[0];
#pragma unroll
            for (int j = 1; j < TS; j++) if (j <= l) m = fmaxf(m, pr[j]);
            float sum = 0.f;
#pragma unroll
            for (int j = 0; j < TS; j++) if (j <= l) { float e = expf(pr[j] - m); pr[j] = e; sum += e; }
#pragma unroll
            for (int j = 0; j < TS; j++) pr[j] = (j <= l) ? pr[j] / sum : 0.f;
        }
        WSYNC();

        // ---- G2[q][e] (own batch): 160 tasks/wave; into Qb (Q2 dead) ----
        for (int oi = l; oi < 160; oi += 64) {
            int q = oi >> 4, e4 = (oi & 15) * 4;
            const float* pp = Pb + (hb * 4 + w) * 120 + q * 12;
            v2f g0 = (v2f)(0.f), g1 = (v2f)(0.f);
#pragma unroll
            for (int k = 0; k < TS; k++) {
                float p = pp[k];
                v2f pv; pv.x = p; pv.y = p;
                float4 v = *(const float4*)(Vb + (w * 10 + k) * QSTR + e4);
                g0 = pv * ((const v2f*)&v)[0] + g0;
                g1 = pv * ((const v2f*)&v)[1] + g1;
            }
            float4 g;
            ((v2f*)&g)[0] = g0; ((v2f*)&g)[1] = g1;
            *(float4*)(Qb + (w * 10 + q) * QSTR + e4) = g;
        }
        WSYNC();

        // ---- out-fold: out[b][n][c] = t1.ZQ[n][c] + s * G2.ZW[n][c] ----
        if (l < 40) {
            int n = l >> 2, c = l & 3;
            const float* tr = Hs + (hb * 40 + w * 10 + n) * HSTR;   // t1 row
            const float* zq = ZQb + (n * 4 + c) * TE;
            v2f s0 = (v2f)(0.f), s1 = (v2f)(0.f);
            for (int k = 0; k < TE; k += 8) {
                float4 ta = *(const float4*)(tr + k);
                float4 za = *(const float4*)(zq + k);
                float4 tc = *(const float4*)(tr + k + 4);
                float4 zc = *(const float4*)(zq + k + 4);
                s0 = ((const v2f*)&ta)[0] * ((const v2f*)&za)[0] + s0;
                s1 = ((const v2f*)&ta)[1] * ((const v2f*)&za)[1] + s1;
                s0 = ((const v2f*)&tc)[0] * ((const v2f*)&zc)[0] + s0;
                s1 = ((const v2f*)&tc)[1] * ((const v2f*)&zc)[1] + s1;
            }
            float base = (s0.x + s0.y) + (s1.x + s1.y);
            const float* gr = Qb + (w * 10 + n) * QSTR;
            const float* zw = ZWb + (n * 4 + c) * TE;
            v2f a0 = (v2f)(0.f), a1 = (v2f)(0.f);
            for (int e = 0; e < TE; e += 8) {
                float4 ga = *(const float4*)(gr + e);
                float4 za = *(const float4*)(zw + e);
                float4 gc = *(const float4*)(gr + e + 4);
                float4 zc = *(const float4*)(zw + e + 4);
                a0 = ((const v2f*)&ga)[0] * ((const v2f*)&za)[0] + a0;
                a1 = ((const v2f*)&ga)[1] * ((const v2f*)&za)[1] + a1;
                a0 = ((const v2f*)&gc)[0] * ((const v2f*)&zc)[0] + a0;
                a1 = ((const v2f*)&gc)[1] * ((const v2f*)&zc)[1] + a1;
            }
            float att = (a0.x + a0.y) + (a1.x + a1.y);
            out[((size_t)(gb0 + hb * 4 + w) * TS + n) * 4 + c] =
                base + att * INVSQRT10;
        }
        __syncthreads();
    } // hb layer 2
}

// ---------------- host launch -----------------------------------------------
extern "C" void kernel_launch(void* const* d_in, const int* in_sizes, int n_in,
                              void* d_out, int out_size, void* d_ws, size_t ws_size,
                              hipStream_t stream) {
    const float* x    = (const float*)d_in[0];
    const float* L_w  = (const float*)d_in[1];
    const float* UL_w = (const float*)d_in[2];
    const float* WQ   = (const float*)d_in[3];
    const float* WK   = (const float*)d_in[4];
    const float* WVd  = (const float*)d_in[5];
    const float* WVu  = (const float*)d_in[6];
    const float* WQ2  = (const float*)d_in[7];
    const float* WK2  = (const float*)d_in[8];
    const float* WVd2 = (const float*)d_in[9];
    const float* WVu2 = (const float*)d_in[10];
    const float* qin1 = (const float*)d_in[11];
    const float* qout1= (const float*)d_in[12];
    const float* qin2 = (const float*)d_in[13];
    const float* qout2= (const float*)d_in[14];
    float* out = (float*)d_out;
    float* POSb = (float*)d_ws;   // WS_* layout (705 KB)

    int B = in_sizes[0] / (TS * 4);
    size_t lds_bytes = (size_t)LDS_FLOATS * sizeof(float);

    (void)hipFuncSetAttribute((const void*)trans_fused,
                              hipFuncAttributeMaxDynamicSharedMemorySize,
                              (int)lds_bytes);

    pre_kernel<<<dim3(111), dim3(256), 0, stream>>>(
        POSb, L_w, WQ, WK, WVd, qin2, qout2, UL_w, WVu2, qin1, WVu,
        qout1, WQ2, WK2, WVd2);
    trans_fused<<<dim3(B / BT), dim3(NTHR), lds_bytes, stream>>>(
        x, L_w, UL_w, WQ, WK, WVd, WVu, WQ2, WK2, WVd2, WVu2,
        qin1, qout1, qin2, qout2, POSb, out);
}

// Round 19
// 555.358 us; speedup vs baseline: 1.1089x; 1.1089x over previous
//
#include <hip/hip_runtime.h>
#include <math.h>

#define TS 10
#define TD 128
#define TE 64
#define BT 4
#define NTHR 256
#define HSTR 68           // Hs row stride: t1 only (64 cols + 4 pad)
#define QSTR 68           // Q/K/Vd/G row stride: 64+4 pad
#define NHROWS (TS*BT)    // 40

#define HS_FLOATS (NHROWS*HSTR)    // 2720
#define BUF_FLOATS (40*QSTR)       // 2720
#define P_FLOATS (BT*TS*12)        // 480
#define LDS_FLOATS (HS_FLOATS + 3*BUF_FLOATS + P_FLOATS)   // 11360 -> 45440 B (3 WG/CU)

#define INVSQRT10 0.31622776601683794f

// workspace float offsets (layout unchanged from R17/R18)
#define WS_POS   0        // POS[10][128]             (1280)  [tables only]
#define WS_LW    1280     // LW[p][c][e] 3x4x64       (768)
#define WS_PW    2048     // PW[p][n][e] 3x10x64      (1920)
#define WS_ZW    3968     // ZW[n][c][e] 10x4x64      (2560)
#define WS_LQ    6528     // LQ[n][c][k] 10x4x64      (2560)
#define WS_PQ    9088     // PQ[n][k]    10x64        (640)
#define WS_ZQ    9728     // ZQ[n][c][k] 10x4x64      (2560)
#define WS_WVUQ  12288    // WVuQ[n][e][k] 10x64x64   (40960)
#define WS_W2N   53248    // W2N[p][n][k][e] 3x10x64x64 (122880) -> end 176128 (705 KB)

typedef float v2f __attribute__((ext_vector_type(2)));

// Broadcast-free packed FMA via VOP3P op_sel (bit-identical IEEE fp32 fma),
// R7-proven; keeps the deep-prefetch gemm spill-free.
#define PKFMA_LO(acc_, ap_, wp_) \
    asm("v_pk_fma_f32 %0, %1, %2, %0 op_sel:[0,0,0] op_sel_hi:[0,1,1]" \
        : "+v"(acc_) : "v"(ap_), "v"(wp_))
#define PKFMA_HI(acc_, ap_, wp_) \
    asm("v_pk_fma_f32 %0, %1, %2, %0 op_sel:[1,0,0] op_sel_hi:[1,1,1]" \
        : "+v"(acc_) : "v"(ap_), "v"(wp_))

// Wave-synchronous LDS fence (R8/R13-validated): sufficient for same-wave
// LDS RAW deps; replaces __syncthreads inside the wave-local attention chain.
#define WSYNC() do { __builtin_amdgcn_wave_barrier(); \
    asm volatile("s_waitcnt lgkmcnt(0)" ::: "memory"); \
    __builtin_amdgcn_wave_barrier(); } while (0)

__device__ __forceinline__ float pos_val(int n, int d) {
    int j = d >> 1;
    double ang = (double)n / pow(1000.0, 2.0 * (double)j / (double)TD);
    return (float)((d & 1) ? cos(ang) : sin(ang));
}

// ---------------- pre-kernel (once per launch, into d_ws) -------------------
// R18 form (111 dependency-free blocks, bench-validated twice):
//   bid 0       : POS table + LW + PW
//   bid 1..10   : per-n {stage qin1[n] -> LDS} then LQ[n], PQ[n], WVuQ[n]
//   bid 11..70  : W2N[p][n] half-k (60 blocks)
//   bid 71..110 : per-(n,c) chain P2row -> Zrow -> {ZW,ZQ} (40 blocks)
__global__ void pre_kernel(float* __restrict__ ws,
                           const float* __restrict__ L_w,
                           const float* __restrict__ WQ,
                           const float* __restrict__ WK,
                           const float* __restrict__ WVd,
                           const float* __restrict__ qin2,
                           const float* __restrict__ qout2,
                           const float* __restrict__ UL_w,
                           const float* __restrict__ WVu2,
                           const float* __restrict__ qin1,
                           const float* __restrict__ WVu,
                           const float* __restrict__ qout1,
                           const float* __restrict__ WQ2,
                           const float* __restrict__ WK2,
                           const float* __restrict__ WVd2) {
    const int tid = threadIdx.x;
    const int bid = blockIdx.x;

    if (bid == 0) {
        __shared__ float sPOS[TS * TD];
        for (int idx = tid; idx < TS * TD; idx += 256) {
            float v = pos_val(idx / TD, idx % TD);
            sPOS[idx] = v;
            ws[WS_POS + idx] = v;
        }
        __syncthreads();
        for (int idx = tid; idx < 3 * 4 * TE; idx += 256) {
            int p = idx >> 8, r = idx & 255, c = r >> 6, e = r & 63;
            const float* Wp = (p == 0 ? WQ : (p == 1 ? WK : WVd));
            const float* lr = L_w + c * TD;
            float acc = 0.f;
            for (int d = 0; d < TD; d++) acc = fmaf(lr[d], Wp[d * TE + e], acc);
            ws[WS_LW + idx] = acc;
        }
        for (int idx = tid; idx < 3 * TS * TE; idx += 256) {
            int p = idx / 640, r = idx % 640, n = r >> 6, e = r & 63;
            const float* Wp = (p == 0 ? WQ : (p == 1 ? WK : WVd));
            const float* pr = sPOS + n * TD;
            float acc = 0.f;
            for (int d = 0; d < TD; d++) acc = fmaf(pr[d], Wp[d * TE + e], acc);
            ws[WS_PW + idx] = acc;
        }
        return;
    }
    if (bid <= 10) {   // per-n: LQ + PQ + WVuQ from LDS-staged qin1[n]
        int n = bid - 1;
        __shared__ float sQ[TD * TE];     // qin1[n] (32 KB)
        __shared__ float sPOSn[TD];
        for (int idx = tid; idx < TD * TE / 4; idx += 256)
            *(float4*)(sQ + idx * 4) =
                *(const float4*)(qin1 + (size_t)n * TD * TE + idx * 4);
        if (tid < TD) sPOSn[tid] = pos_val(n, tid);
        __syncthreads();
        for (int t = tid; t < 320; t += 256) {
            if (t < 256) {
                int c = t >> 6, k = t & 63;
                const float* lr = L_w + c * TD;
                float acc = 0.f;
                for (int d = 0; d < TD; d++) acc = fmaf(lr[d], sQ[d * TE + k], acc);
                ws[WS_LQ + n * 256 + t] = acc;
            } else {
                int k = t - 256;
                float acc = 0.f;
                for (int d = 0; d < TD; d++) acc = fmaf(sPOSn[d], sQ[d * TE + k], acc);
                ws[WS_PQ + n * TE + k] = acc;
            }
        }
        float* dst = ws + WS_WVUQ + n * 4096;
        for (int idx = tid; idx < TE * TE; idx += 256) {
            int e = idx >> 6, k = idx & 63;
            const float* wv = WVu + (size_t)e * TD;
            float acc = 0.f;
            for (int d = 0; d < TD; d += 4) {
                float4 w4 = *(const float4*)(wv + d);
                acc = fmaf(w4.x, sQ[(d + 0) * TE + k], acc);
                acc = fmaf(w4.y, sQ[(d + 1) * TE + k], acc);
                acc = fmaf(w4.z, sQ[(d + 2) * TE + k], acc);
                acc = fmaf(w4.w, sQ[(d + 3) * TE + k], acc);
            }
            dst[idx] = acc;
        }
        return;
    }
    if (bid <= 70) {   // W2N[p][n], half-k per block
        int t = bid - 11;
        int half = t & 1, pn = t >> 1;
        int p = pn / 10, n = pn % 10;
        const float* Wp = (p == 0 ? WQ2 : (p == 1 ? WK2 : WVd2));
        float* dst = ws + WS_W2N + (pn << 12);
        for (int idx = tid; idx < 2048; idx += 256) {
            int k = half * 32 + (idx >> 6), e = idx & 63;
            const float* qp = qout1 + ((size_t)n * TE + k) * TD;
            float acc = 0.f;
            for (int j = 0; j < TD; j += 4) {
                float4 q4 = *(const float4*)(qp + j);
                acc = fmaf(q4.x, Wp[(j + 0) * TE + e], acc);
                acc = fmaf(q4.y, Wp[(j + 1) * TE + e], acc);
                acc = fmaf(q4.z, Wp[(j + 2) * TE + e], acc);
                acc = fmaf(q4.w, Wp[(j + 3) * TE + e], acc);
            }
            dst[k * TE + e] = acc;
        }
        return;
    }
    // bid 71..110: (n,c) chain: P2 row -> Z row -> ZW + ZQ rows
    {
        int t = bid - 71, n = t >> 2, c = t & 3;
        __shared__ float sP2r[TE];
        __shared__ float sZr[TD];
        if (tid < TE) {
            int i = tid;
            const float* qp = qout2 + ((size_t)n * TE + i) * TD;
            float acc = 0.f;
            for (int d = 0; d < TD; d += 4) {
                float4 q4 = *(const float4*)(qp + d);
                acc = fmaf(q4.x, UL_w[(d + 0) * 4 + c], acc);
                acc = fmaf(q4.y, UL_w[(d + 1) * 4 + c], acc);
                acc = fmaf(q4.z, UL_w[(d + 2) * 4 + c], acc);
                acc = fmaf(q4.w, UL_w[(d + 3) * 4 + c], acc);
            }
            sP2r[i] = acc;
        }
        __syncthreads();
        if (tid < TD) {
            int j = tid;
            const float* ip = qin2 + ((size_t)n * TD + j) * TE;
            float acc = 0.f;
            for (int i = 0; i < TE; i += 4) {
                float4 q4 = *(const float4*)(ip + i);
                acc = fmaf(q4.x, sP2r[i + 0], acc);
                acc = fmaf(q4.y, sP2r[i + 1], acc);
                acc = fmaf(q4.z, sP2r[i + 2], acc);
                acc = fmaf(q4.w, sP2r[i + 3], acc);
            }
            sZr[j] = acc;
        }
        __syncthreads();
        if (tid < TE) {
            int e = tid;
            const float* wp = WVu2 + (size_t)e * TD;
            float acc = 0.f;
            for (int j = 0; j < TD; j += 4) {
                float4 w4 = *(const float4*)(wp + j);
                acc = fmaf(w4.x, sZr[j + 0], acc);
                acc = fmaf(w4.y, sZr[j + 1], acc);
                acc = fmaf(w4.z, sZr[j + 2], acc);
                acc = fmaf(w4.w, sZr[j + 3], acc);
            }
            ws[WS_ZW + (n * 4 + c) * TE + e] = acc;
        } else if (tid < 2 * TE) {
            int k = tid - TE;
            const float* qp = qout1 + ((size_t)n * TE + k) * TD;
            float acc = 0.f;
            for (int j = 0; j < TD; j += 4) {
                float4 q4 = *(const float4*)(qp + j);
                acc = fmaf(q4.x, sZr[j + 0], acc);
                acc = fmaf(q4.y, sZr[j + 1], acc);
                acc = fmaf(q4.z, sZr[j + 2], acc);
                acc = fmaf(q4.w, sZr[j + 3], acc);
            }
            ws[WS_ZQ + (n * 4 + c) * TE + k] = acc;
        }
    }
}

// ---------------- M-row x C-col fp32 GEMM tile, packed-pair FMAs ------------
// Deep W-prefetch (R5/R6) + op_sel pk-fma (R7): spill-free.
template <int M, int SPLIT, int C, int K, bool ADD>
__device__ __forceinline__ void gemm_f32(
    const float* __restrict__ Ap, int a0, int aHi, int aLo,
    const float* __restrict__ W, int ws,
    float* __restrict__ Op, int o0, int oHi, int oLo,
    float scale)
{
    static_assert(C % 4 == 0, "C must be a multiple of 4");
    static_assert(K % 16 == 0 && K >= 32, "K must be a multiple of 16, >=32");
    constexpr int CG = C / 4;   // float4 groups
    constexpr int CP = C / 2;   // float2 pairs
    v2f acc[M][CP];
#pragma unroll
    for (int m = 0; m < M; m++)
#pragma unroll
        for (int p = 0; p < CP; p++) acc[m][p] = (v2f)(0.f);

    float4 aR0[M], aR1[M];
    float4 wA[8 * CG], wB[8 * CG];      // ping-pong 8-k W buffers
    const float* ap = Ap + a0;
    const float* wp = W;

    auto loadW8 = [&](float4* wR, const float* w) {
#pragma unroll
        for (int kk = 0; kk < 8; kk++)
#pragma unroll
            for (int cg = 0; cg < CG; cg++)
                wR[kk * CG + cg] = *(const float4*)(w + kk * ws + cg * 4);
    };
    auto loadA = [&](float4* aR, const float* a) {
#pragma unroll
        for (int m = 0; m < M; m++)
            aR[m] = *(const float4*)(a + (m / SPLIT) * aHi + (m % SPLIT) * aLo);
    };
    auto computeH = [&](const float4* aR, const float4* wR) {
#pragma unroll
        for (int m = 0; m < M; m++) {
            const v2f* ap2 = (const v2f*)&aR[m];    // (a0,a1),(a2,a3)
#pragma unroll
            for (int kp = 0; kp < 2; kp++) {
                const v2f* wf0 = (const v2f*)&wR[(2 * kp + 0) * CG];
                const v2f* wf1 = (const v2f*)&wR[(2 * kp + 1) * CG];
#pragma unroll
                for (int p = 0; p < CP; p++) {
                    PKFMA_LO(acc[m][p], ap2[kp], wf0[p]);   // k = 2kp
                    PKFMA_HI(acc[m][p], ap2[kp], wf1[p]);   // k = 2kp+1
                }
            }
        }
    };

    loadW8(wA, wp);
    loadA(aR0, ap);
#pragma unroll 1
    for (int k = 0; k + 16 < K; k += 16) {
        loadW8(wB, wp + 8 * ws);
        loadA(aR1, ap + 4);
        computeH(aR0, wA);
        loadA(aR0, ap + 8);
        computeH(aR1, wA + 4 * CG);
        loadW8(wA, wp + 16 * ws);
        loadA(aR1, ap + 12);
        computeH(aR0, wB);
        loadA(aR0, ap + 16);
        computeH(aR1, wB + 4 * CG);
        wp += 16 * ws; ap += 16;
    }
    loadW8(wB, wp + 8 * ws);
    loadA(aR1, ap + 4);
    computeH(aR0, wA);
    loadA(aR0, ap + 8);
    computeH(aR1, wA + 4 * CG);
    loadA(aR1, ap + 12);
    computeH(aR0, wB);
    computeH(aR1, wB + 4 * CG);

    v2f s2; s2.x = scale; s2.y = scale;
#pragma unroll
    for (int m = 0; m < M; m++) {
        float* op = Op + o0 + (m / SPLIT) * oHi + (m % SPLIT) * oLo;
#pragma unroll
        for (int cg = 0; cg < CG; cg++) {
            float4 r;
            v2f* rp = (v2f*)&r;
            if constexpr (ADD) {
                float4 v = *(float4*)(op + cg * 4);
                const v2f* vp = (const v2f*)&v;
                rp[0] = s2 * acc[m][cg * 2 + 0] + vp[0];
                rp[1] = s2 * acc[m][cg * 2 + 1] + vp[1];
            } else {
                rp[0] = s2 * acc[m][cg * 2 + 0];
                rp[1] = s2 * acc[m][cg * 2 + 1];
            }
            *(float4*)(op + cg * 4) = r;
        }
    }
}

// ---------------- fused kernel ----------------------------------------------
// R19 = R16-18 kernel body at BT=4, hb loop deleted:
//   - LDS 45.44 KB (Hs shrunk to t1-only 40x68) -> 3 WG/CU, 12 waves/CU,
//     THREE independent barrier domains (vs two).
//   - Table traffic UNCHANGED: BT=8 read W2N/WVuQ twice (hb loop); BT=4
//     reads them once, and 2x the WGs -> same total bytes.
//   - Same phase decompositions (256-thread shapes carry over verbatim).
// VGPR 84 (R16-measured) << 128; launch_bounds(256,2) retains the proven cap.
extern "C" __global__ __launch_bounds__(NTHR, 2)
void trans_fused(const float* __restrict__ x,
                 const float* __restrict__ L_w, const float* __restrict__ UL_w,
                 const float* __restrict__ WQ,  const float* __restrict__ WK,
                 const float* __restrict__ WVd, const float* __restrict__ WVu,
                 const float* __restrict__ WQ2, const float* __restrict__ WK2,
                 const float* __restrict__ WVd2,const float* __restrict__ WVu2,
                 const float* __restrict__ qin1,const float* __restrict__ qout1,
                 const float* __restrict__ qin2,const float* __restrict__ qout2,
                 const float* __restrict__ POSb, float* __restrict__ out)
{
    extern __shared__ float lds[];
    float* Hs = lds;                      // [40][HSTR]; t1 (persistent)
    float* Qb = lds + HS_FLOATS;          // [40][QSTR]; Q then G
    float* Kb = Qb + BUF_FLOATS;          // [40][QSTR]
    float* Vb = Kb + BUF_FLOATS;          // [40][QSTR] Vd
    float* Pb = Vb + BUF_FLOATS;          // [4][10][12] logits -> softmax weights

    const int tid = threadIdx.x;
    const int vtid = (tid + ((blockIdx.x & 3) << 6)) & 255;  // rotate idle windows
    const int w = vtid >> 6;              // wave-local batch index (wave-aligned)
    const int l = vtid & 63;
    const int gb0 = blockIdx.x * BT;
    const float* LWb   = POSb + WS_LW;
    const float* PWb   = POSb + WS_PW;
    const float* ZWb   = POSb + WS_ZW;
    const float* LQb   = POSb + WS_LQ;
    const float* PQb   = POSb + WS_PQ;
    const float* ZQb   = POSb + WS_ZQ;
    const float* WVuQb = POSb + WS_WVUQ;
    const float* W2Nb  = POSb + WS_W2N;

    // ================= LAYER 1 (h never materialized) =================
    // ---- QKV-l1 rank-4 (1920 tasks) + t1base = x@LQ + PQ (640 tasks) ----
    for (int t = vtid; t < 2560; t += NTHR) {
        if (t < 1920) {
            int p = t / 640, r2 = t % 640, rr = r2 >> 4, e4 = r2 & 15;
            int b4 = rr / 10, n = rr - b4 * 10;
            const float* xp = x + ((size_t)(gb0 + b4) * TS + n) * 4;
            float4 x4 = *(const float4*)xp;
            const float* xf = (const float*)&x4;
            const float* lw = LWb + p * 256 + e4 * 4;
            float4 pw = *(const float4*)(PWb + p * 640 + n * 64 + e4 * 4);
            v2f a0 = ((const v2f*)&pw)[0], a1 = ((const v2f*)&pw)[1];
#pragma unroll
            for (int c = 0; c < 4; c++) {
                float4 l4 = *(const float4*)(lw + c * 64);
                v2f xb; xb.x = xf[c]; xb.y = xf[c];
                a0 = xb * ((const v2f*)&l4)[0] + a0;
                a1 = xb * ((const v2f*)&l4)[1] + a1;
            }
            float* Ob = (p == 0 ? Qb : (p == 1 ? Kb : Vb));
            float4 r4;
            ((v2f*)&r4)[0] = a0; ((v2f*)&r4)[1] = a1;
            *(float4*)(Ob + rr * QSTR + e4 * 4) = r4;
        } else {
            int t2 = t - 1920;              // 0..639
            int rr = t2 >> 4, cg = t2 & 15;
            int b4 = rr / 10, n = rr - b4 * 10;
            const float* xp = x + ((size_t)(gb0 + b4) * TS + n) * 4;
            float4 x4 = *(const float4*)xp;
            const float* xf = (const float*)&x4;
            const float* lq = LQb + n * 256 + cg * 4;
            float4 pq = *(const float4*)(PQb + n * 64 + cg * 4);
            v2f a0 = ((const v2f*)&pq)[0], a1 = ((const v2f*)&pq)[1];
#pragma unroll
            for (int c = 0; c < 4; c++) {
                float4 l4 = *(const float4*)(lq + c * 64);
                v2f xb; xb.x = xf[c]; xb.y = xf[c];
                a0 = xb * ((const v2f*)&l4)[0] + a0;
                a1 = xb * ((const v2f*)&l4)[1] + a1;
            }
            float4 r4;
            ((v2f*)&r4)[0] = a0; ((v2f*)&r4)[1] = a1;
            *(float4*)(Hs + rr * HSTR + cg * 4) = r4;
        }
    }
    __syncthreads();

    // ---- logits: 55 (i,j<=i) pairs, one lane each; own batch ----
    if (l < 55) {
        int i = 0, base = 0, pr = l;
        while (pr >= base + i + 1) { base += i + 1; i++; }
        int j = pr - base;
        const float* qr = Qb + (w * 10 + i) * QSTR;
        const float* kr = Kb + (w * 10 + j) * QSTR;
        v2f s0 = (v2f)(0.f), s1 = (v2f)(0.f);
        for (int e = 0; e < TE; e += 8) {
            float4 qa = *(const float4*)(qr + e);
            float4 ka = *(const float4*)(kr + e);
            float4 qc = *(const float4*)(qr + e + 4);
            float4 kc = *(const float4*)(kr + e + 4);
            s0 = ((const v2f*)&qa)[0] * ((const v2f*)&ka)[0] + s0;
            s1 = ((const v2f*)&qa)[1] * ((const v2f*)&ka)[1] + s1;
            s0 = ((const v2f*)&qc)[0] * ((const v2f*)&kc)[0] + s0;
            s1 = ((const v2f*)&qc)[1] * ((const v2f*)&kc)[1] + s1;
        }
        Pb[w * 120 + i * 12 + j] = (s0.x + s0.y) + (s1.x + s1.y);
    }
    WSYNC();

    // ---- softmax over keys j<=i (own batch) ----
    if (l < TS) {
        float* pr = Pb + w * 120 + l * 12;
        float m = pr[0];
#pragma unroll
        for (int j = 1; j < TS; j++) if (j <= l) m = fmaxf(m, pr[j]);
        float sum = 0.f;
#pragma unroll
        for (int j = 0; j < TS; j++) if (j <= l) { float e = expf(pr[j] - m); pr[j] = e; sum += e; }
#pragma unroll
        for (int j = 0; j < TS; j++) pr[j] = (j <= l) ? pr[j] / sum : 0.f;
    }
    WSYNC();

    // ---- G[q][e] (own batch): 160 tasks per wave; into Qb (Q dead) ----
    for (int oi = l; oi < 160; oi += 64) {
        int q = oi >> 4, e4 = (oi & 15) * 4;
        const float* pp = Pb + w * 120 + q * 12;
        v2f g0 = (v2f)(0.f), g1 = (v2f)(0.f);
#pragma unroll
        for (int k = 0; k < TS; k++) {
            float p = pp[k];
            v2f pv; pv.x = p; pv.y = p;
            float4 v = *(const float4*)(Vb + (w * 10 + k) * QSTR + e4);
            g0 = pv * ((const v2f*)&v)[0] + g0;
            g1 = pv * ((const v2f*)&v)[1] + g1;
        }
        float4 g;
        ((v2f*)&g)[0] = g0; ((v2f*)&g)[1] = g1;
        *(float4*)(Qb + (w * 10 + q) * QSTR + e4) = g;
    }
    __syncthreads();   // t1gemm groups rows across waves (M=4 over b4)

    // ---- t1 += s * G @ WVuQ[n]: 160 tasks = n(10) x cg(16), M=4, K=64 ----
    if (vtid < 160) {
        int n = vtid >> 4, cg = vtid & 15;
        gemm_f32<4, 1, 4, TE, true>(
            Qb, n * QSTR, 10 * QSTR, 0,
            WVuQb + n * 4096 + cg * 4, TE,
            Hs, n * HSTR + cg * 4, 10 * HSTR, 0,
            INVSQRT10);
    }
    __syncthreads();

    // ================= LAYER 2 (rank-64 collapsed; t1 stays in Hs) ==========
    // ---- QKV-l2: Q2/K2/V2 = t1 @ W2N[p][n]; 480 tasks, M=4, K=64 ----
    for (int t = vtid; t < 480; t += NTHR) {
        int p = t / 160, rem = t - p * 160, n = rem >> 4, cg = rem & 15;
        float* Ob = (p == 0 ? Qb : (p == 1 ? Kb : Vb));
        gemm_f32<4, 1, 4, TE, false>(
            Hs, n * HSTR, 10 * HSTR, 0,
            W2Nb + ((p * 10 + n) << 12) + cg * 4, TE,
            Ob, n * QSTR + cg * 4, 10 * QSTR, 0, 1.f);
    }
    __syncthreads();

    // ---- logits2 (wave-local) ----
    if (l < 55) {
        int i = 0, base = 0, pr = l;
        while (pr >= base + i + 1) { base += i + 1; i++; }
        int j = pr - base;
        const float* qr = Qb + (w * 10 + i) * QSTR;
        const float* kr = Kb + (w * 10 + j) * QSTR;
        v2f s0 = (v2f)(0.f), s1 = (v2f)(0.f);
        for (int e = 0; e < TE; e += 8) {
            float4 qa = *(const float4*)(qr + e);
            float4 ka = *(const float4*)(kr + e);
            float4 qc = *(const float4*)(qr + e + 4);
            float4 kc = *(const float4*)(kr + e + 4);
            s0 = ((const v2f*)&qa)[0] * ((const v2f*)&ka)[0] + s0;
            s1 = ((const v2f*)&qa)[1] * ((const v2f*)&ka)[1] + s1;
            s0 = ((const v2f*)&qc)[0] * ((const v2f*)&kc)[0] + s0;
            s1 = ((const v2f*)&qc)[1] * ((const v2f*)&kc)[1] + s1;
        }
        Pb[w * 120 + i * 12 + j] = (s0.x + s0.y) + (s1.x + s1.y);
    }
    WSYNC();

    // ---- softmax2 (own batch) ----
    if (l < TS) {
        float* pr = Pb + w * 120 + l * 12;
        float m = pr[0];
#pragma unroll
        for (int j = 1; j < TS; j++) if (j <= l) m = fmaxf(m, pr[j]);
        float sum = 0.f;
#pragma unroll
        for (int j = 0; j < TS; j++) if (j <= l) { float e = expf(pr[j] - m); pr[j] = e; sum += e; }
#pragma unroll
        for (int j = 0; j < TS; j++) pr[j] = (j <= l) ? pr[j] / sum : 0.f;
    }
    WSYNC();

    // ---- G2[q][e] (own batch): 160 tasks/wave; into Qb (Q2 dead) ----
    for (int oi = l; oi < 160; oi += 64) {
        int q = oi >> 4, e4 = (oi & 15) * 4;
        const float* pp = Pb + w * 120 + q * 12;
        v2f g0 = (v2f)(0.f), g1 = (v2f)(0.f);
#pragma unroll
        for (int k = 0; k < TS; k++) {
            float p = pp[k];
            v2f pv; pv.x = p; pv.y = p;
            float4 v = *(const float4*)(Vb + (w * 10 + k) * QSTR + e4);
            g0 = pv * ((const v2f*)&v)[0] + g0;
            g1 = pv * ((const v2f*)&v)[1] + g1;
        }
        float4 g;
        ((v2f*)&g)[0] = g0; ((v2f*)&g)[1] = g1;
        *(float4*)(Qb + (w * 10 + q) * QSTR + e4) = g;
    }
    WSYNC();

    // ---- out-fold: out[b][n][c] = t1.ZQ[n][c] + s * G2.ZW[n][c] ----
    if (l < 40) {
        int n = l >> 2, c = l & 3;
        const float* tr = Hs + (w * 10 + n) * HSTR;   // t1 row
        const float* zq = ZQb + (n * 4 + c) * TE;
        v2f s0 = (v2f)(0.f), s1 = (v2f)(0.f);
        for (int k = 0; k < TE; k += 8) {
            float4 ta = *(const float4*)(tr + k);
            float4 za = *(const float4*)(zq + k);
            float4 tc = *(const float4*)(tr + k + 4);
            float4 zc = *(const float4*)(zq + k + 4);
            s0 = ((const v2f*)&ta)[0] * ((const v2f*)&za)[0] + s0;
            s1 = ((const v2f*)&ta)[1] * ((const v2f*)&za)[1] + s1;
            s0 = ((const v2f*)&tc)[0] * ((const v2f*)&zc)[0] + s0;
            s1 = ((const v2f*)&tc)[1] * ((const v2f*)&zc)[1] + s1;
        }
        float base = (s0.x + s0.y) + (s1.x + s1.y);
        const float* gr = Qb + (w * 10 + n) * QSTR;
        const float* zw = ZWb + (n * 4 + c) * TE;
        v2f a0 = (v2f)(0.f), a1 = (v2f)(0.f);
        for (int e = 0; e < TE; e += 8) {
            float4 ga = *(const float4*)(gr + e);
            float4 za = *(const float4*)(zw + e);
            float4 gc = *(const float4*)(gr + e + 4);
            float4 zc = *(const float4*)(zw + e + 4);
            a0 = ((const v2f*)&ga)[0] * ((const v2f*)&za)[0] + a0;
            a1 = ((const v2f*)&ga)[1] * ((const v2f*)&za)[1] + a1;
            a0 = ((const v2f*)&gc)[0] * ((const v2f*)&zc)[0] + a0;
            a1 = ((const v2f*)&gc)[1] * ((const v2f*)&zc)[1] + a1;
        }
        float att = (a0.x + a0.y) + (a1.x + a1.y);
        out[((size_t)(gb0 + w) * TS + n) * 4 + c] = base + att * INVSQRT10;
    }
}

// ---------------- host launch -----------------------------------------------
extern "C" void kernel_launch(void* const* d_in, const int* in_sizes, int n_in,
                              void* d_out, int out_size, void* d_ws, size_t ws_size,
                              hipStream_t stream) {
    const float* x    = (const float*)d_in[0];
    const float* L_w  = (const float*)d_in[1];
    const float* UL_w = (const float*)d_in[2];
    const float* WQ   = (const float*)d_in[3];
    const float* WK   = (const float*)d_in[4];
    const float* WVd  = (const float*)d_in[5];
    const float* WVu  = (const float*)d_in[6];
    const float* WQ2  = (const float*)d_in[7];
    const float* WK2  = (const float*)d_in[8];
    const float* WVd2 = (const float*)d_in[9];
    const float* WVu2 = (const float*)d_in[10];
    const float* qin1 = (const float*)d_in[11];
    const float* qout1= (const float*)d_in[12];
    const float* qin2 = (const float*)d_in[13];
    const float* qout2= (const float*)d_in[14];
    float* out = (float*)d_out;
    float* POSb = (float*)d_ws;   // WS_* layout (705 KB)

    int B = in_sizes[0] / (TS * 4);
    size_t lds_bytes = (size_t)LDS_FLOATS * sizeof(float);

    (void)hipFuncSetAttribute((const void*)trans_fused,
                              hipFuncAttributeMaxDynamicSharedMemorySize,
                              (int)lds_bytes);

    pre_kernel<<<dim3(111), dim3(256), 0, stream>>>(
        POSb, L_w, WQ, WK, WVd, qin2, qout2, UL_w, WVu2, qin1, WVu,
        qout1, WQ2, WK2, WVd2);
    trans_fused<<<dim3(B / BT), dim3(NTHR), lds_bytes, stream>>>(
        x, L_w, UL_w, WQ, WK, WVd, WVu, WQ2, WK2, WVd2, WVu2,
        qin1, qout1, qin2, qout2, POSb, out);
}